// Round 1
// baseline (2009.255 us; speedup 1.0000x reference)
//
#include <hip/hip_runtime.h>

#define B_SZ 32
#define H_SZ 64
#define W_SZ 64
#define DIM 64
#define K_CODES 512
#define N_VEC (B_SZ * H_SZ * W_SZ)   // 131072
#define CHUNK 128                     // codebook rows staged in LDS per pass
#define Q_OFF 1
#define PERP_OFF 8388609
#define ENC_OFF 8388610

// ---------------------------------------------------------------------------
// Kernel 1: per-vector argmin over the codebook (f32, matches reference
// formula ||x||^2 - 2 x.e + ||e||^2), fused with:
//   - idx[i] write
//   - counts histogram (global atomics)
//   - dw segment-sum scatter (global atomics, x already in registers)
//   - one-hot 1.0f scatter into pre-zeroed encodings output
// ---------------------------------------------------------------------------
__global__ __launch_bounds__(256) void argmin_scatter_kernel(
    const float* __restrict__ inputs,
    const float* __restrict__ emb_w,
    int* __restrict__ idx,
    float* __restrict__ counts,
    float* __restrict__ dw,
    float* __restrict__ enc)
{
    __shared__ float sE[CHUNK * DIM];   // 32 KB
    __shared__ float sEE[CHUNK];

    const int i = blockIdx.x * 256 + threadIdx.x;

    // Load x into registers (64 VGPRs), compute ||x||^2.
    float x[DIM];
    const float4* xp = reinterpret_cast<const float4*>(inputs + (size_t)i * DIM);
    float xx0 = 0.f, xx1 = 0.f, xx2 = 0.f, xx3 = 0.f;
#pragma unroll
    for (int d4 = 0; d4 < DIM / 4; ++d4) {
        float4 v = xp[d4];
        x[4 * d4 + 0] = v.x; x[4 * d4 + 1] = v.y;
        x[4 * d4 + 2] = v.z; x[4 * d4 + 3] = v.w;
        xx0 = fmaf(v.x, v.x, xx0); xx1 = fmaf(v.y, v.y, xx1);
        xx2 = fmaf(v.z, v.z, xx2); xx3 = fmaf(v.w, v.w, xx3);
    }
    const float xx = (xx0 + xx1) + (xx2 + xx3);

    float best = 3.4e38f;
    int bestk = 0;

    for (int c = 0; c < K_CODES / CHUNK; ++c) {
        __syncthreads();
        // Cooperative stage of CHUNK codebook rows (32 KB) into LDS.
        {
            const float4* ep =
                reinterpret_cast<const float4*>(emb_w + (size_t)c * CHUNK * DIM);
            float4* sp = reinterpret_cast<float4*>(sE);
#pragma unroll
            for (int r = 0; r < (CHUNK * DIM / 4) / 256; ++r)
                sp[r * 256 + threadIdx.x] = ep[r * 256 + threadIdx.x];
        }
        __syncthreads();
        // ||e||^2 per staged row.
        if (threadIdx.x < CHUNK) {
            const float* e = sE + threadIdx.x * DIM;
            float s0 = 0, s1 = 0, s2 = 0, s3 = 0;
#pragma unroll
            for (int d = 0; d < DIM; d += 4) {
                s0 = fmaf(e[d + 0], e[d + 0], s0);
                s1 = fmaf(e[d + 1], e[d + 1], s1);
                s2 = fmaf(e[d + 2], e[d + 2], s2);
                s3 = fmaf(e[d + 3], e[d + 3], s3);
            }
            sEE[threadIdx.x] = (s0 + s1) + (s2 + s3);
        }
        __syncthreads();

        // 128 dot products; LDS reads are wave-uniform -> broadcast (free).
        for (int k = 0; k < CHUNK; ++k) {
            const float4* e4 = reinterpret_cast<const float4*>(sE + k * DIM);
            float a0 = 0, a1 = 0, a2 = 0, a3 = 0;
#pragma unroll
            for (int d4 = 0; d4 < DIM / 4; ++d4) {
                float4 e = e4[d4];
                a0 = fmaf(x[4 * d4 + 0], e.x, a0);
                a1 = fmaf(x[4 * d4 + 1], e.y, a1);
                a2 = fmaf(x[4 * d4 + 2], e.z, a2);
                a3 = fmaf(x[4 * d4 + 3], e.w, a3);
            }
            const float dot = (a0 + a1) + (a2 + a3);
            const float dist = (xx - 2.f * dot) + sEE[k];
            if (dist < best) { best = dist; bestk = c * CHUNK + k; }  // strict < : first-min like argmin
        }
    }

    idx[i] = bestk;
    atomicAdd(&counts[bestk], 1.0f);
    enc[(size_t)i * K_CODES + bestk] = 1.0f;

    float* dwrow = dw + (size_t)bestk * DIM;
#pragma unroll
    for (int d = 0; d < DIM; ++d)
        atomicAdd(&dwrow[d], x[d]);
}

// ---------------------------------------------------------------------------
// Kernel 2: EMA cluster-size + Laplace smoothing + codebook update +
// perplexity. One block of K=512 threads.
// ---------------------------------------------------------------------------
__global__ __launch_bounds__(512) void ema_update_kernel(
    const float* __restrict__ counts,
    const float* __restrict__ ema_cs,
    const float* __restrict__ ema_w,
    const float* __restrict__ dw,
    float* __restrict__ new_emb,
    float* __restrict__ perp_out)
{
    __shared__ float red[K_CODES];
    const int k = threadIdx.x;

    const float cnt = counts[k];
    float cs = ema_cs[k] * 0.99f + 0.01f * cnt;

    red[k] = cs;
    __syncthreads();
    for (int s = K_CODES / 2; s > 0; s >>= 1) {
        if (k < s) red[k] += red[k + s];
        __syncthreads();
    }
    const float n = red[0];
    __syncthreads();

    cs = (cs + 1e-5f) / (n + (float)K_CODES * 1e-5f) * n;

    for (int d = 0; d < DIM; ++d) {
        const float v = ema_w[k * DIM + d] * 0.99f + 0.01f * dw[k * DIM + d];
        new_emb[k * DIM + d] = v / cs;
    }

    // perplexity = exp(-sum p log(p + 1e-10)), p = counts / N (N = 2^17, exact)
    const float p = cnt * (1.0f / (float)N_VEC);
    red[k] = p * logf(p + 1e-10f);
    __syncthreads();
    for (int s = K_CODES / 2; s > 0; s >>= 1) {
        if (k < s) red[k] += red[k + s];
        __syncthreads();
    }
    if (k == 0) perp_out[0] = expf(-red[0]);
}

// ---------------------------------------------------------------------------
// Kernel 3: gather quantized = new_emb[idx], straight-through qst = x+(q-x),
// NHWC -> NCHW transpose via LDS tile, commitment-loss partial sums.
// One block per (b, h); 256 threads handle the 64x64 (w, d) tile.
// ---------------------------------------------------------------------------
__global__ __launch_bounds__(256) void quantize_kernel(
    const float* __restrict__ inputs,
    const int* __restrict__ idx,
    const float* __restrict__ new_emb,
    float* __restrict__ out_q,
    float* __restrict__ loss_accum)
{
    __shared__ int sIdx[W_SZ];
    __shared__ float tile[DIM][W_SZ + 1];  // +1 pad: transpose write is 2-way (free)
    __shared__ float wsum[4];

    const int bh = blockIdx.x;
    const int b = bh >> 6, h = bh & 63;
    const int t = threadIdx.x;

    if (t < W_SZ) sIdx[t] = idx[bh * W_SZ + t];
    __syncthreads();

    const float* inRow = inputs + (size_t)bh * W_SZ * DIM;
    const int d = t & 63;
    const int wg = t >> 6;
    float lsum = 0.f;
#pragma unroll
    for (int p = 0; p < 16; ++p) {
        const int w = wg * 16 + p;
        const float xv = inRow[w * DIM + d];               // coalesced in d
        const float qv = new_emb[sIdx[w] * DIM + d];       // wave-uniform row, L1/L2 hot
        const float diff = qv - xv;
        tile[d][w] = xv + diff;                             // qst = x + (q - x), as reference
        lsum = fmaf(diff, diff, lsum);
    }
    __syncthreads();

    const int w2 = t & 63;
    const int dg = t >> 6;
#pragma unroll
    for (int p = 0; p < 16; ++p) {
        const int d2 = dg * 16 + p;
        out_q[(((size_t)b * DIM + d2) * H_SZ + h) * W_SZ + w2] = tile[d2][w2];  // coalesced in w
    }

    for (int off = 32; off > 0; off >>= 1) lsum += __shfl_down(lsum, off);
    if ((t & 63) == 0) wsum[t >> 6] = lsum;
    __syncthreads();
    if (t == 0) atomicAdd(loss_accum, (wsum[0] + wsum[1]) + (wsum[2] + wsum[3]));
}

__global__ void finalize_kernel(const float* __restrict__ loss_accum,
                                float* __restrict__ out_loss)
{
    out_loss[0] = 0.25f * (loss_accum[0] / 8388608.0f);
}

// ---------------------------------------------------------------------------
extern "C" void kernel_launch(void* const* d_in, const int* in_sizes, int n_in,
                              void* d_out, int out_size, void* d_ws, size_t ws_size,
                              hipStream_t stream)
{
    const float* inputs = (const float*)d_in[0];
    const float* emb_w  = (const float*)d_in[1];
    const float* ema_cs = (const float*)d_in[2];
    const float* ema_w  = (const float*)d_in[3];
    float* out = (float*)d_out;
    float* ws  = (float*)d_ws;

    // Workspace layout (element offsets in f32):
    int*   idxbuf = (int*)ws;            // [0, 131072)   encoding indices
    float* counts = ws + 131072;         // [131072, 131584)
    float* dwbuf  = ws + 131584;         // [131584, 164352)
    float* nemb   = ws + 164352;         // [164352, 197120)  (16B-aligned)
    float* lossac = ws + 197120;         // [197120]

    // Per-call zeroing (harness does not re-poison between replays).
    hipMemsetAsync(counts, 0, (512 + 512 * DIM) * sizeof(float), stream);
    hipMemsetAsync(lossac, 0, sizeof(float), stream);
    hipMemsetAsync(out + ENC_OFF, 0, (size_t)N_VEC * K_CODES * sizeof(float), stream);

    argmin_scatter_kernel<<<N_VEC / 256, 256, 0, stream>>>(
        inputs, emb_w, idxbuf, counts, dwbuf, out + ENC_OFF);

    ema_update_kernel<<<1, K_CODES, 0, stream>>>(
        counts, ema_cs, ema_w, dwbuf, nemb, out + PERP_OFF);

    quantize_kernel<<<B_SZ * H_SZ, 256, 0, stream>>>(
        inputs, idxbuf, nemb, out + Q_OFF, lossac);

    finalize_kernel<<<1, 1, 0, stream>>>(lossac, out);
}

// Round 2
// 275.736 us; speedup vs baseline: 7.2869x; 7.2869x over previous
//
#include <hip/hip_runtime.h>

#define B_SZ 32
#define H_SZ 64
#define W_SZ 64
#define DIM 64
#define K_CODES 512
#define N_VEC (B_SZ * H_SZ * W_SZ)   // 131072
#define VPB 64                        // vectors per block
#define KC 128                        // codes per LDS chunk
#define NCHUNK (K_CODES / KC)         // 4
#define Q_OFF 1
#define PERP_OFF 8388609
#define ENC_OFF 8388610

// ---------------------------------------------------------------------------
// Kernel 1: register-tiled f32 distance GEMM + argmin, fused with idx write,
// counts histogram, dw segment-sum (row-contiguous atomics), one-hot scatter.
//
// Block: 256 threads = 16 tv x 16 tc. Thread tile: 4 vectors x 8 codes.
// LDS: X tile 64x64 f32 (float4 granules, col ^= (v>>2) swizzle),
//      E chunk 128x64 f32 (col ^= (k&15) swizzle).
// Distance formula matches reference: ||x||^2 - 2 x.e + ||e||^2.
// Tie rule: strict < with ascending-k scan, cross-thread reduce prefers
// smaller k on equal dist == numpy argmin (first minimum).
// ---------------------------------------------------------------------------
__global__ __launch_bounds__(256) void argmin_scatter_kernel(
    const float* __restrict__ inputs,
    const float* __restrict__ emb_w,
    int* __restrict__ idx,
    float* __restrict__ counts,
    float* __restrict__ dw,
    float* __restrict__ enc)
{
    __shared__ float4 sX[VPB * 16];    // 16 KB
    __shared__ float4 sE[KC * 16];     // 32 KB
    __shared__ float  sXX[VPB];
    __shared__ float  sEE[KC];
    __shared__ int    sBK[VPB];
    float* sRbest = (float*)sE;                 // overlay after chunk loop
    int*   sRk    = ((int*)sE) + VPB * 16;

    const int t  = threadIdx.x;
    const int tv = t & 15;             // vector-group id
    const int tc = t >> 4;             // code-group id
    const int v0 = tv * 4;
    const int k0 = tc * 8;
    const int vecbase = blockIdx.x * VPB;

    // ---- stage X tile (64 vec x 64 d), swizzled granules ----
    {
        const float4* inp4 = reinterpret_cast<const float4*>(
            inputs + (size_t)vecbase * DIM);
#pragma unroll
        for (int r = 0; r < 4; ++r) {
            const int g = r * 256 + t;           // 0..1023, = v*16 + d4
            const int v = g >> 4, d4 = g & 15;
            sX[v * 16 + (d4 ^ (v >> 2))] = inp4[g];
        }
    }
    __syncthreads();

    // ---- ||x||^2 per staged vector ----
    if (t < VPB) {
        const int v = t;
        float s0 = 0, s1 = 0, s2 = 0, s3 = 0;
#pragma unroll
        for (int d4 = 0; d4 < 16; ++d4) {
            const float4 q = sX[v * 16 + (d4 ^ (v >> 2))];
            s0 = fmaf(q.x, q.x, s0); s1 = fmaf(q.y, q.y, s1);
            s2 = fmaf(q.z, q.z, s2); s3 = fmaf(q.w, q.w, s3);
        }
        sXX[v] = (s0 + s1) + (s2 + s3);
    }

    float best[4]  = {3.4e38f, 3.4e38f, 3.4e38f, 3.4e38f};
    int   bestk[4] = {0, 0, 0, 0};

    for (int ch = 0; ch < NCHUNK; ++ch) {
        // ---- stage E chunk (128 codes x 64 d), swizzled ----
        {
            const float4* eb4 = reinterpret_cast<const float4*>(
                emb_w + (size_t)ch * KC * DIM);
#pragma unroll
            for (int r = 0; r < 8; ++r) {
                const int g = r * 256 + t;       // 0..2047, = k*16 + d4
                const int k = g >> 4, d4 = g & 15;
                sE[k * 16 + (d4 ^ (k & 15))] = eb4[g];
            }
        }
        __syncthreads();   // A: sE ready (also: prior dist reads of sEE done)

        // ---- ||e||^2 per chunk row (threads 0..127) ----
        if (t < KC) {
            const int k = t;
            float s0 = 0, s1 = 0, s2 = 0, s3 = 0;
#pragma unroll
            for (int d4 = 0; d4 < 16; ++d4) {
                const float4 q = sE[k * 16 + (d4 ^ (k & 15))];
                s0 = fmaf(q.x, q.x, s0); s1 = fmaf(q.y, q.y, s1);
                s2 = fmaf(q.z, q.z, s2); s3 = fmaf(q.w, q.w, s3);
            }
            sEE[k] = (s0 + s1) + (s2 + s3);
        }

        // ---- register-tiled dot products: 4 vec x 8 codes ----
        float acc[4][8];
#pragma unroll
        for (int i = 0; i < 4; ++i)
#pragma unroll
            for (int c = 0; c < 8; ++c) acc[i][c] = 0.f;

#pragma unroll 4
        for (int d4 = 0; d4 < 16; ++d4) {
            float4 xv[4];
#pragma unroll
            for (int i = 0; i < 4; ++i)
                xv[i] = sX[(v0 + i) * 16 + (d4 ^ tv)];   // (v0+i)>>2 == tv
#pragma unroll
            for (int c = 0; c < 8; ++c) {
                const float4 ev = sE[(k0 + c) * 16 + (d4 ^ ((k0 + c) & 15))];
#pragma unroll
                for (int i = 0; i < 4; ++i) {
                    acc[i][c] = fmaf(xv[i].x, ev.x, acc[i][c]);
                    acc[i][c] = fmaf(xv[i].y, ev.y, acc[i][c]);
                    acc[i][c] = fmaf(xv[i].z, ev.z, acc[i][c]);
                    acc[i][c] = fmaf(xv[i].w, ev.w, acc[i][c]);
                }
            }
        }
        __syncthreads();   // B: sEE visible, all sE reads done

        // ---- distances + running argmin (ascending k within thread) ----
#pragma unroll
        for (int c = 0; c < 8; ++c) {
            const int k = ch * KC + k0 + c;
            const float ee = sEE[k0 + c];
#pragma unroll
            for (int i = 0; i < 4; ++i) {
                const float dist = (sXX[v0 + i] - 2.f * acc[i][c]) + ee;
                if (dist < best[i]) { best[i] = dist; bestk[i] = k; }
            }
        }
    }

    // ---- cross-thread argmin reduce over the 16 tc groups ----
    __syncthreads();                   // everyone past last sEE read
#pragma unroll
    for (int i = 0; i < 4; ++i) {
        sRbest[(v0 + i) * 16 + tc] = best[i];
        sRk   [(v0 + i) * 16 + tc] = bestk[i];
    }
    __syncthreads();

    if (t < VPB) {
        const int v = t;
        float b = sRbest[v * 16];
        int  bk = sRk[v * 16];
#pragma unroll
        for (int j = 1; j < 16; ++j) {
            const float bj = sRbest[v * 16 + j];
            const int   kj = sRk[v * 16 + j];
            if (bj < b || (bj == b && kj < bk)) { b = bj; bk = kj; }
        }
        sBK[v] = bk;
        idx[vecbase + v] = bk;
        atomicAdd(&counts[bk], 1.0f);
        enc[(size_t)(vecbase + v) * K_CODES + bk] = 1.0f;
    }
    __syncthreads();

    // ---- dw segment-sum: one contiguous 64-float row per wave-instruction ----
    {
        const int d  = t & 63;
        const int vp = t >> 6;
#pragma unroll
        for (int p = 0; p < 16; ++p) {
            const int v = p * 4 + vp;
            const int g = v * 16 + ((d >> 2) ^ (v >> 2));
            const float xval = reinterpret_cast<const float*>(sX)[g * 4 + (d & 3)];
            atomicAdd(&dw[(size_t)sBK[v] * DIM + d], xval);
        }
    }
}

// ---------------------------------------------------------------------------
// Kernel 2: EMA cluster-size + Laplace smoothing + codebook update +
// perplexity. One block of K=512 threads.
// ---------------------------------------------------------------------------
__global__ __launch_bounds__(512) void ema_update_kernel(
    const float* __restrict__ counts,
    const float* __restrict__ ema_cs,
    const float* __restrict__ ema_w,
    const float* __restrict__ dw,
    float* __restrict__ new_emb,
    float* __restrict__ perp_out)
{
    __shared__ float red[K_CODES];
    const int k = threadIdx.x;

    const float cnt = counts[k];
    float cs = ema_cs[k] * 0.99f + 0.01f * cnt;

    red[k] = cs;
    __syncthreads();
    for (int s = K_CODES / 2; s > 0; s >>= 1) {
        if (k < s) red[k] += red[k + s];
        __syncthreads();
    }
    const float n = red[0];
    __syncthreads();

    cs = (cs + 1e-5f) / (n + (float)K_CODES * 1e-5f) * n;

    for (int d = 0; d < DIM; ++d) {
        const float v = ema_w[k * DIM + d] * 0.99f + 0.01f * dw[k * DIM + d];
        new_emb[k * DIM + d] = v / cs;
    }

    const float p = cnt * (1.0f / (float)N_VEC);
    red[k] = p * logf(p + 1e-10f);
    __syncthreads();
    for (int s = K_CODES / 2; s > 0; s >>= 1) {
        if (k < s) red[k] += red[k + s];
        __syncthreads();
    }
    if (k == 0) perp_out[0] = expf(-red[0]);
}

// ---------------------------------------------------------------------------
// Kernel 3: gather quantized = new_emb[idx], straight-through qst,
// NHWC -> NCHW via LDS tile, commitment-loss partials.
// ---------------------------------------------------------------------------
__global__ __launch_bounds__(256) void quantize_kernel(
    const float* __restrict__ inputs,
    const int* __restrict__ idx,
    const float* __restrict__ new_emb,
    float* __restrict__ out_q,
    float* __restrict__ loss_accum)
{
    __shared__ int sIdx[W_SZ];
    __shared__ float tile[DIM][W_SZ + 1];
    __shared__ float wsum[4];

    const int bh = blockIdx.x;
    const int b = bh >> 6, h = bh & 63;
    const int t = threadIdx.x;

    if (t < W_SZ) sIdx[t] = idx[bh * W_SZ + t];
    __syncthreads();

    const float* inRow = inputs + (size_t)bh * W_SZ * DIM;
    const int d = t & 63;
    const int wg = t >> 6;
    float lsum = 0.f;
#pragma unroll
    for (int p = 0; p < 16; ++p) {
        const int w = wg * 16 + p;
        const float xv = inRow[w * DIM + d];
        const float qv = new_emb[sIdx[w] * DIM + d];
        const float diff = qv - xv;
        tile[d][w] = xv + diff;
        lsum = fmaf(diff, diff, lsum);
    }
    __syncthreads();

    const int w2 = t & 63;
    const int dg = t >> 6;
#pragma unroll
    for (int p = 0; p < 16; ++p) {
        const int d2 = dg * 16 + p;
        out_q[(((size_t)b * DIM + d2) * H_SZ + h) * W_SZ + w2] = tile[d2][w2];
    }

    for (int off = 32; off > 0; off >>= 1) lsum += __shfl_down(lsum, off);
    if ((t & 63) == 0) wsum[t >> 6] = lsum;
    __syncthreads();
    if (t == 0) atomicAdd(loss_accum, (wsum[0] + wsum[1]) + (wsum[2] + wsum[3]));
}

__global__ void finalize_kernel(const float* __restrict__ loss_accum,
                                float* __restrict__ out_loss)
{
    out_loss[0] = 0.25f * (loss_accum[0] / 8388608.0f);
}

// ---------------------------------------------------------------------------
extern "C" void kernel_launch(void* const* d_in, const int* in_sizes, int n_in,
                              void* d_out, int out_size, void* d_ws, size_t ws_size,
                              hipStream_t stream)
{
    const float* inputs = (const float*)d_in[0];
    const float* emb_w  = (const float*)d_in[1];
    const float* ema_cs = (const float*)d_in[2];
    const float* ema_w  = (const float*)d_in[3];
    float* out = (float*)d_out;
    float* ws  = (float*)d_ws;

    int*   idxbuf = (int*)ws;            // [0, 131072)
    float* counts = ws + 131072;         // [131072, 131584)
    float* dwbuf  = ws + 131584;         // [131584, 164352)
    float* nemb   = ws + 164352;         // [164352, 197120)
    float* lossac = ws + 197120;         // [197120]

    hipMemsetAsync(counts, 0, (512 + 512 * DIM) * sizeof(float), stream);
    hipMemsetAsync(lossac, 0, sizeof(float), stream);
    hipMemsetAsync(out + ENC_OFF, 0, (size_t)N_VEC * K_CODES * sizeof(float), stream);

    argmin_scatter_kernel<<<N_VEC / VPB, 256, 0, stream>>>(
        inputs, emb_w, idxbuf, counts, dwbuf, out + ENC_OFF);

    ema_update_kernel<<<1, K_CODES, 0, stream>>>(
        counts, ema_cs, ema_w, dwbuf, nemb, out + PERP_OFF);

    quantize_kernel<<<B_SZ * H_SZ, 256, 0, stream>>>(
        inputs, idxbuf, nemb, out + Q_OFF, lossac);

    finalize_kernel<<<1, 1, 0, stream>>>(lossac, out);
}